// Round 1
// baseline (1281.904 us; speedup 1.0000x reference)
//
#include <hip/hip_runtime.h>
#include <cstdint>

#define NTOK 4096
#define CDIM 1024
#define DDIM 4096
#define NEXP 8
#define PAIR_CAP 9216  // 8192 pairs + 8*128 padding worst case

typedef __bf16 bf16x8 __attribute__((ext_vector_type(8)));
typedef float f32x4 __attribute__((ext_vector_type(4)));
typedef unsigned int u32x4 __attribute__((ext_vector_type(4)));
typedef unsigned short u16;

__device__ __forceinline__ u16 bf16_rne(float f) {
  unsigned u = __builtin_bit_cast(unsigned, f);
  u += 0x7fffu + ((u >> 16) & 1u);
  return (u16)(u >> 16);
}
__device__ __forceinline__ unsigned pk2(float a, float b) {
  return (unsigned)bf16_rne(a) | ((unsigned)bf16_rne(b) << 16);
}
__device__ __forceinline__ bf16x8 ldfrag(const u16* p) {
  u32x4 v = *(const u32x4*)p;
  return __builtin_bit_cast(bf16x8, v);
}

typedef __attribute__((address_space(1))) const unsigned int as1_u32;
typedef __attribute__((address_space(3))) unsigned int as3_u32;
__device__ __forceinline__ void gload_lds16(const void* g, void* l) {
  __builtin_amdgcn_global_load_lds((as1_u32*)g, (as3_u32*)l, 16, 0, 0);
}

// ---------------- router: fp32 logits, softmax-top2 renorm ----------------
__global__ void k_router(const float* __restrict__ x, const float* __restrict__ wr,
                         int2* __restrict__ topi, float2* __restrict__ topw) {
  int n = blockIdx.x;
  int lane = threadIdx.x;  // 64 threads = 1 wave per token
  const float* xr = x + (size_t)n * CDIM;
  float acc[NEXP];
#pragma unroll
  for (int e = 0; e < NEXP; ++e) acc[e] = 0.f;
  for (int c = lane; c < CDIM; c += 64) {
    float xv = xr[c];
#pragma unroll
    for (int e = 0; e < NEXP; ++e) acc[e] += xv * wr[e * CDIM + c];
  }
#pragma unroll
  for (int e = 0; e < NEXP; ++e) {
    float v = acc[e];
#pragma unroll
    for (int off = 32; off > 0; off >>= 1) v += __shfl_xor(v, off, 64);
    acc[e] = v;
  }
  if (lane == 0) {
    int i1 = 0; float l1 = acc[0];
#pragma unroll
    for (int e = 1; e < NEXP; ++e) if (acc[e] > l1) { l1 = acc[e]; i1 = e; }
    int i2 = (i1 == 0) ? 1 : 0; float l2 = acc[i2];
#pragma unroll
    for (int e = 0; e < NEXP; ++e)
      if (e != i1 && acc[e] > l2) { l2 = acc[e]; i2 = e; }
    float wa = 1.f / (1.f + expf(l2 - l1));  // == p1/(p1+p2)
    topi[n] = make_int2(i1, i2);
    topw[n] = make_float2(wa, 1.f - wa);
  }
}

// ---------------- bucketing ----------------
__global__ void k_count(const int2* __restrict__ topi, int* __restrict__ counts) {
  int n = blockIdx.x * blockDim.x + threadIdx.x;
  if (n < NTOK) {
    int2 tv = topi[n];
    atomicAdd(&counts[tv.x], 1);
    atomicAdd(&counts[tv.y], 1);
  }
}

__global__ void k_scan(const int* __restrict__ counts, int* __restrict__ poff,
                       int* __restrict__ cursor) {
  if (threadIdx.x == 0 && blockIdx.x == 0) {
    int o = 0;
    for (int e = 0; e < NEXP; ++e) {
      poff[e] = o;
      cursor[e] = o;
      o += (counts[e] + 127) & ~127;  // pad each expert segment to 128 rows
    }
    poff[NEXP] = o;
  }
}

__global__ void k_scatter(const int2* __restrict__ topi, const float2* __restrict__ topw,
                          int* __restrict__ cursor, int* __restrict__ ptok,
                          float* __restrict__ pw) {
  int n = blockIdx.x * blockDim.x + threadIdx.x;
  if (n < NTOK) {
    int2 tv = topi[n];
    float2 wv = topw[n];
    int p0 = atomicAdd(&cursor[tv.x], 1); ptok[p0] = n; pw[p0] = wv.x;
    int p1 = atomicAdd(&cursor[tv.y], 1); ptok[p1] = n; pw[p1] = wv.y;
  }
}

// ---------------- x fp32 -> bf16 ----------------
__global__ void k_xcast(const float* __restrict__ x, u16* __restrict__ xb) {
  int i = blockIdx.x * blockDim.x + threadIdx.x;  // NTOK*CDIM/4 threads
  float4 v = ((const float4*)x)[i];
  ushort4 o;
  o.x = bf16_rne(v.x); o.y = bf16_rne(v.y); o.z = bf16_rne(v.z); o.w = bf16_rne(v.w);
  ((ushort4*)xb)[i] = o;
}

// ---------------- GEMM1: h = gelu(gather(x) @ w1[e] + b1[e]) ----------------
// Tile 128x128, BK=64. LDS [row][k] bf16, 8 blocks of 8 k-elems per row,
// physical block = (kb + (row&7)) & 7  -> conflict-free b128 store AND read.
__global__ __launch_bounds__(256) void k_gemm1(
    const u16* __restrict__ xb, const float* __restrict__ w1,
    const float* __restrict__ b1, const int* __restrict__ counts,
    const int* __restrict__ poff, const int* __restrict__ ptok,
    u16* __restrict__ h) {
  int e = blockIdx.z;
  int cnt = counts[e];
  int cap = (cnt + 127) & ~127;
  if ((int)blockIdx.x * 128 >= cap) return;
  int pairbase = poff[e] + blockIdx.x * 128;
  int colbase = blockIdx.y * 128;

  __shared__ __align__(16) u16 As[128 * 64];
  __shared__ __align__(16) u16 Bs[128 * 64];

  int t = threadIdx.x;
  int wid = t >> 6, lane = t & 63;
  int quad = lane >> 4, lm = lane & 15, l7 = lane & 7;
  int wm = wid & 1, wn = wid >> 1;

  // A gather bases: lane -> (row = wid*32 + i*8 + (lane>>3), chunk q = lane&7)
  // source logical k-block kbl chosen so it lands at physical slot q (swizzle inverse)
  int rl = lane >> 3, q = lane & 7;
  const char* xbc = (const char*)xb;
  uint64_t gA[4];
#pragma unroll
  for (int i = 0; i < 4; ++i) {
    int row = wid * 32 + i * 8 + rl;
    int tok = ptok[pairbase + row];
    int kbl = (q - rl) & 7;
    gA[i] = (uint64_t)tok * (CDIM * 2) + (uint64_t)kbl * 16;
  }

  int nl = t & 127, kh = t >> 7;
  const float* Bp = w1 + (size_t)e * CDIM * DDIM + (size_t)(kh * 32) * DDIM + colbase + nl;

  f32x4 acc[4][4];
  f32x4 zed = {0.f, 0.f, 0.f, 0.f};
#pragma unroll
  for (int a = 0; a < 4; ++a)
#pragma unroll
    for (int b = 0; b < 4; ++b) acc[a][b] = zed;

  for (int step = 0; step < CDIM / 64; ++step) {
    __syncthreads();
#pragma unroll
    for (int i = 0; i < 4; ++i)
      gload_lds16(xbc + gA[i] + (uint64_t)step * 128, (void*)&As[(wid * 32 + i * 8) * 64]);

    const float* bp = Bp + (size_t)step * 64 * DDIM;
#pragma unroll
    for (int kb4 = 0; kb4 < 4; ++kb4) {
      float f0 = bp[(kb4 * 8 + 0) * DDIM], f1 = bp[(kb4 * 8 + 1) * DDIM];
      float f2 = bp[(kb4 * 8 + 2) * DDIM], f3 = bp[(kb4 * 8 + 3) * DDIM];
      float f4 = bp[(kb4 * 8 + 4) * DDIM], f5 = bp[(kb4 * 8 + 5) * DDIM];
      float f6 = bp[(kb4 * 8 + 6) * DDIM], f7 = bp[(kb4 * 8 + 7) * DDIM];
      u32x4 v = {pk2(f0, f1), pk2(f2, f3), pk2(f4, f5), pk2(f6, f7)};
      int kb = kh * 4 + kb4;
      int phys = (kb + (nl & 7)) & 7;
      *(u32x4*)&Bs[nl * 64 + phys * 8] = v;
    }
    __syncthreads();

#pragma unroll
    for (int s = 0; s < 2; ++s) {
      bf16x8 af[4], bfr[4];
#pragma unroll
      for (int tm = 0; tm < 4; ++tm) {
        int row = wm * 64 + tm * 16 + lm;
        int phys = (s * 4 + quad + l7) & 7;
        af[tm] = ldfrag(&As[row * 64 + phys * 8]);
      }
#pragma unroll
      for (int tn = 0; tn < 4; ++tn) {
        int col = wn * 64 + tn * 16 + lm;
        int phys = (s * 4 + quad + l7) & 7;
        bfr[tn] = ldfrag(&Bs[col * 64 + phys * 8]);
      }
#pragma unroll
      for (int tm = 0; tm < 4; ++tm)
#pragma unroll
        for (int tn = 0; tn < 4; ++tn)
          acc[tm][tn] = __builtin_amdgcn_mfma_f32_16x16x32_bf16(af[tm], bfr[tn], acc[tm][tn], 0, 0, 0);
    }
  }

  // epilogue: exact GELU, store bf16 h. C/D layout: col=lane&15, row=quad*4+i
#pragma unroll
  for (int tn = 0; tn < 4; ++tn) {
    int col = colbase + wn * 64 + tn * 16 + lm;
    float b1v = b1[e * DDIM + col];
#pragma unroll
    for (int tm = 0; tm < 4; ++tm) {
      int row0 = pairbase + wm * 64 + tm * 16 + quad * 4;
#pragma unroll
      for (int i = 0; i < 4; ++i) {
        float vv = acc[tm][tn][i] + b1v;
        float g = 0.5f * vv * (1.f + erff(vv * 0.70710678118654752f));
        h[(size_t)(row0 + i) * DDIM + col] = bf16_rne(g);
      }
    }
  }
}

// ---------------- GEMM2: out += w * (h @ w2[e] + b2[e]) ----------------
__global__ __launch_bounds__(256) void k_gemm2(
    const u16* __restrict__ h, const float* __restrict__ w2,
    const float* __restrict__ b2, const int* __restrict__ counts,
    const int* __restrict__ poff, const int* __restrict__ ptok,
    const float* __restrict__ pw, float* __restrict__ out) {
  int e = blockIdx.z;
  int cnt = counts[e];
  int cap = (cnt + 127) & ~127;
  if ((int)blockIdx.x * 128 >= cap) return;
  int pairbase = poff[e] + blockIdx.x * 128;
  int colbase = blockIdx.y * 128;

  __shared__ __align__(16) u16 As[128 * 64];
  __shared__ __align__(16) u16 Bs[128 * 64];

  int t = threadIdx.x;
  int wid = t >> 6, lane = t & 63;
  int quad = lane >> 4, lm = lane & 15, l7 = lane & 7;
  int wm = wid & 1, wn = wid >> 1;

  int rl = lane >> 3, q = lane & 7;
  const char* hc = (const char*)h;
  uint64_t gA[4];
#pragma unroll
  for (int i = 0; i < 4; ++i) {
    int row = wid * 32 + i * 8 + rl;
    int kbl = (q - rl) & 7;
    gA[i] = (uint64_t)(pairbase + row) * (DDIM * 2) + (uint64_t)kbl * 16;
  }

  int nl = t & 127, kh = t >> 7;
  const float* Bp = w2 + (size_t)e * DDIM * CDIM + (size_t)(kh * 32) * CDIM + colbase + nl;

  f32x4 acc[4][4];
  f32x4 zed = {0.f, 0.f, 0.f, 0.f};
#pragma unroll
  for (int a = 0; a < 4; ++a)
#pragma unroll
    for (int b = 0; b < 4; ++b) acc[a][b] = zed;

  for (int step = 0; step < DDIM / 64; ++step) {
    __syncthreads();
#pragma unroll
    for (int i = 0; i < 4; ++i)
      gload_lds16(hc + gA[i] + (uint64_t)step * 128, (void*)&As[(wid * 32 + i * 8) * 64]);

    const float* bp = Bp + (size_t)step * 64 * CDIM;
#pragma unroll
    for (int kb4 = 0; kb4 < 4; ++kb4) {
      float f0 = bp[(kb4 * 8 + 0) * CDIM], f1 = bp[(kb4 * 8 + 1) * CDIM];
      float f2 = bp[(kb4 * 8 + 2) * CDIM], f3 = bp[(kb4 * 8 + 3) * CDIM];
      float f4 = bp[(kb4 * 8 + 4) * CDIM], f5 = bp[(kb4 * 8 + 5) * CDIM];
      float f6 = bp[(kb4 * 8 + 6) * CDIM], f7 = bp[(kb4 * 8 + 7) * CDIM];
      u32x4 v = {pk2(f0, f1), pk2(f2, f3), pk2(f4, f5), pk2(f6, f7)};
      int kb = kh * 4 + kb4;
      int phys = (kb + (nl & 7)) & 7;
      *(u32x4*)&Bs[nl * 64 + phys * 8] = v;
    }
    __syncthreads();

#pragma unroll
    for (int s = 0; s < 2; ++s) {
      bf16x8 af[4], bfr[4];
#pragma unroll
      for (int tm = 0; tm < 4; ++tm) {
        int row = wm * 64 + tm * 16 + lm;
        int phys = (s * 4 + quad + l7) & 7;
        af[tm] = ldfrag(&As[row * 64 + phys * 8]);
      }
#pragma unroll
      for (int tn = 0; tn < 4; ++tn) {
        int col = wn * 64 + tn * 16 + lm;
        int phys = (s * 4 + quad + l7) & 7;
        bfr[tn] = ldfrag(&Bs[col * 64 + phys * 8]);
      }
#pragma unroll
      for (int tm = 0; tm < 4; ++tm)
#pragma unroll
        for (int tn = 0; tn < 4; ++tn)
          acc[tm][tn] = __builtin_amdgcn_mfma_f32_16x16x32_bf16(af[tm], bfr[tn], acc[tm][tn], 0, 0, 0);
    }
  }

  // epilogue: weighted scatter-add into out (pad rows carry w=0)
#pragma unroll
  for (int tm = 0; tm < 4; ++tm) {
    int tokv[4]; float wv[4];
#pragma unroll
    for (int i = 0; i < 4; ++i) {
      int prow = pairbase + wm * 64 + tm * 16 + quad * 4 + i;
      tokv[i] = ptok[prow];
      wv[i] = pw[prow];
    }
#pragma unroll
    for (int tn = 0; tn < 4; ++tn) {
      int col = colbase + wn * 64 + tn * 16 + lm;
      float b2v = b2[e * CDIM + col];
#pragma unroll
      for (int i = 0; i < 4; ++i)
        atomicAdd(out + (size_t)tokv[i] * CDIM + col, wv[i] * (acc[tm][tn][i] + b2v));
    }
  }
}

// ---------------- launch ----------------
extern "C" void kernel_launch(void* const* d_in, const int* in_sizes, int n_in,
                              void* d_out, int out_size, void* d_ws, size_t ws_size,
                              hipStream_t stream) {
  const float* x  = (const float*)d_in[0];
  const float* wr = (const float*)d_in[1];
  const float* w1 = (const float*)d_in[2];
  const float* b1 = (const float*)d_in[3];
  const float* w2 = (const float*)d_in[4];
  const float* b2 = (const float*)d_in[5];
  float* out = (float*)d_out;
  char* ws = (char*)d_ws;

  // ws layout (total ~84 MB)
  int*    counts = (int*)(ws + 0);          //   8 ints
  int*    poff   = (int*)(ws + 64);         //   9 ints
  int*    cursor = (int*)(ws + 128);        //   8 ints
  int2*   topi   = (int2*)(ws + 256);       //  32 KB
  float2* topw   = (float2*)(ws + 33024);   //  32 KB
  int*    ptok   = (int*)(ws + 65792);      //  36 KB
  float*  pw     = (float*)(ws + 102656);   //  36 KB
  u16*    xb     = (u16*)(ws + 139520);     //   8 MB
  u16*    h      = (u16*)(ws + 8528128);    // ~75.5 MB

  hipMemsetAsync(ws, 0, 256, stream);               // counts/poff/cursor
  hipMemsetAsync(ws + 65792, 0, 73728, stream);     // ptok+pw (padding = tok 0, w 0)
  hipMemsetAsync(d_out, 0, (size_t)NTOK * CDIM * 4, stream);

  k_router<<<NTOK, 64, 0, stream>>>(x, wr, topi, topw);
  k_count<<<NTOK / 256, 256, 0, stream>>>(topi, counts);
  k_scan<<<1, 64, 0, stream>>>(counts, poff, cursor);
  k_scatter<<<NTOK / 256, 256, 0, stream>>>(topi, topw, cursor, ptok, pw);
  k_xcast<<<NTOK * CDIM / 4 / 256, 256, 0, stream>>>(x, xb);
  k_gemm1<<<dim3(32, DDIM / 128, NEXP), 256, 0, stream>>>(xb, w1, b1, counts, poff, ptok, h);
  k_gemm2<<<dim3(32, CDIM / 128, NEXP), 256, 0, stream>>>(h, w2, b2, counts, poff, ptok, pw, out);
}

// Round 2
// 695.055 us; speedup vs baseline: 1.8443x; 1.8443x over previous
//
#include <hip/hip_runtime.h>
#include <cstdint>

#define NTOK 4096
#define CDIM 1024
#define DDIM 4096
#define NEXP 8
#define PAIR_CAP 9216  // 8192 pairs + 8*127 rounding < 9216
#define MAXTILE 72

typedef __bf16 bf16x8 __attribute__((ext_vector_type(8)));
typedef float f32x4 __attribute__((ext_vector_type(4)));
typedef unsigned int u32x4 __attribute__((ext_vector_type(4)));
typedef unsigned short u16;

__device__ __forceinline__ u16 bf16_rne(float f) {
  unsigned u = __builtin_bit_cast(unsigned, f);
  u += 0x7fffu + ((u >> 16) & 1u);
  return (u16)(u >> 16);
}
__device__ __forceinline__ unsigned pk2(float a, float b) {
  return (unsigned)bf16_rne(a) | ((unsigned)bf16_rne(b) << 16);
}
__device__ __forceinline__ float bf2f(u16 v) {
  unsigned u = (unsigned)v << 16;
  return __builtin_bit_cast(float, u);
}
__device__ __forceinline__ bf16x8 ldfrag(const u16* p) {
  u32x4 v = *(const u32x4*)p;
  return __builtin_bit_cast(bf16x8, v);
}

typedef __attribute__((address_space(1))) const unsigned int as1_u32;
typedef __attribute__((address_space(3))) unsigned int as3_u32;
__device__ __forceinline__ void gload_lds16(const void* g, void* l) {
  __builtin_amdgcn_global_load_lds((as1_u32*)g, (as3_u32*)l, 16, 0, 0);
}

// ---------------- router: fp32 logits, softmax-top2 renorm ----------------
__global__ void k_router(const float* __restrict__ x, const float* __restrict__ wr,
                         int2* __restrict__ topi, float2* __restrict__ topw) {
  int n = blockIdx.x;
  int lane = threadIdx.x;  // 1 wave per token
  const float* xr = x + (size_t)n * CDIM;
  float acc[NEXP];
#pragma unroll
  for (int e = 0; e < NEXP; ++e) acc[e] = 0.f;
  for (int c = lane; c < CDIM; c += 64) {
    float xv = xr[c];
#pragma unroll
    for (int e = 0; e < NEXP; ++e) acc[e] += xv * wr[e * CDIM + c];
  }
#pragma unroll
  for (int e = 0; e < NEXP; ++e) {
    float v = acc[e];
#pragma unroll
    for (int off = 32; off > 0; off >>= 1) v += __shfl_xor(v, off, 64);
    acc[e] = v;
  }
  if (lane == 0) {
    int i1 = 0; float l1 = acc[0];
#pragma unroll
    for (int e = 1; e < NEXP; ++e) if (acc[e] > l1) { l1 = acc[e]; i1 = e; }
    int i2 = (i1 == 0) ? 1 : 0; float l2 = acc[i2];
#pragma unroll
    for (int e = 0; e < NEXP; ++e)
      if (e != i1 && acc[e] > l2) { l2 = acc[e]; i2 = e; }
    float wa = 1.f / (1.f + expf(l2 - l1));  // p1/(p1+p2)
    topi[n] = make_int2(i1, i2);
    topw[n] = make_float2(wa, 1.f - wa);
  }
}

// ---------------- bucketing ----------------
__global__ void k_count(const int2* __restrict__ topi, int* __restrict__ counts) {
  int n = blockIdx.x * blockDim.x + threadIdx.x;
  if (n < NTOK) {
    int2 tv = topi[n];
    atomicAdd(&counts[tv.x], 1);
    atomicAdd(&counts[tv.y], 1);
  }
}

__global__ void k_scan(const int* __restrict__ counts, int* __restrict__ poff,
                       int* __restrict__ cursor, int* __restrict__ ntiles,
                       int* __restrict__ tile_e, int* __restrict__ tile_base) {
  if (threadIdx.x == 0 && blockIdx.x == 0) {
    int o = 0, nt = 0;
    for (int e = 0; e < NEXP; ++e) {
      poff[e] = o;
      cursor[e] = o;
      int cap = (counts[e] + 127) & ~127;
      for (int tb = 0; tb < cap; tb += 128) { tile_e[nt] = e; tile_base[nt] = o + tb; ++nt; }
      o += cap;
    }
    poff[NEXP] = o;
    *ntiles = nt;
  }
}

__global__ void k_scatter(const int2* __restrict__ topi,
                          int* __restrict__ cursor, int* __restrict__ ptok,
                          int2* __restrict__ ppos) {
  int n = blockIdx.x * blockDim.x + threadIdx.x;
  if (n < NTOK) {
    int2 tv = topi[n];
    int p0 = atomicAdd(&cursor[tv.x], 1); ptok[p0] = n;
    int p1 = atomicAdd(&cursor[tv.y], 1); ptok[p1] = n;
    ppos[n] = make_int2(p0, p1);
  }
}

// ---------------- x fp32 -> bf16 ----------------
__global__ void k_xcast(const float* __restrict__ x, u16* __restrict__ xb) {
  int i = blockIdx.x * blockDim.x + threadIdx.x;
  float4 v = ((const float4*)x)[i];
  ushort4 o;
  o.x = bf16_rne(v.x); o.y = bf16_rne(v.y); o.z = bf16_rne(v.z); o.w = bf16_rne(v.w);
  ((ushort4*)xb)[i] = o;
}

// ---------------- weight transpose+cast: fp32 [E][K][N] -> bf16 [E][N][K] ----
__global__ __launch_bounds__(256) void k_transpose(const float* __restrict__ in,
                                                   u16* __restrict__ out, int K, int N) {
  __shared__ float tile[64][65];
  int e = blockIdx.z;
  int nb = blockIdx.x * 64, kb = blockIdx.y * 64;
  const float* src = in + (size_t)e * K * N + (size_t)kb * N + nb;
  int t = threadIdx.x;
#pragma unroll
  for (int j = 0; j < 4; ++j) {
    int idx4 = t + j * 256;               // 1024 float4s = 64x64 floats
    int r = idx4 >> 4, c4 = idx4 & 15;
    float4 v = *(const float4*)&src[(size_t)r * N + c4 * 4];
    tile[r][c4 * 4 + 0] = v.x; tile[r][c4 * 4 + 1] = v.y;
    tile[r][c4 * 4 + 2] = v.z; tile[r][c4 * 4 + 3] = v.w;
  }
  __syncthreads();
  u16* dst = out + (size_t)e * N * K + (size_t)nb * K + kb;
#pragma unroll
  for (int j = 0; j < 8; ++j) {
    int idxp = t + j * 256;               // 2048 ushort2 = 64x64 bf16
    int n = idxp >> 5, kp = idxp & 31;
    unsigned pr = pk2(tile[kp * 2][n], tile[kp * 2 + 1][n]);
    *(unsigned*)&dst[(size_t)n * K + kp * 2] = pr;
  }
}

// ---------------- unified MFMA GEMM (m97 structure) ----------------
// Out[row][col] = (A[arow] . WT[e][col]) + bias[e][col], optional exact GELU.
// A: bf16 [*, KD] (arow = gathered token or direct pair row)
// WT: bf16 [E][NOUT][KD]  (pre-transposed weights)
// 128x128 tile, BK=64, both operands staged via global_load_lds dwordx4.
// LDS layout: row*64 u16, 8 k-blocks of 8, physical blk = (kb + (row&7)) & 7.
template <int KD, int NOUT, bool GATHER, bool DOGELU>
__global__ __launch_bounds__(256) void k_gemm(
    const u16* __restrict__ A, const u16* __restrict__ WT,
    const float* __restrict__ bias, const int* __restrict__ ntiles,
    const int* __restrict__ tile_e, const int* __restrict__ tile_base,
    const int* __restrict__ ptok, u16* __restrict__ Out) {
  int bx = blockIdx.x;
  if (bx >= *ntiles) return;
  int e = tile_e[bx];
  int pairbase = tile_base[bx];
  int colbase = blockIdx.y * 128;

  __shared__ __align__(16) u16 As[128 * 64];
  __shared__ __align__(16) u16 Bs[128 * 64];

  int t = threadIdx.x;
  int wid = t >> 6, lane = t & 63;
  int quad = lane >> 4, lm = lane & 15, l7 = lane & 7;
  int wm = wid & 1, wn = wid >> 1;
  int rl = lane >> 3, q = lane & 7;
  int kbl = (q - rl) & 7;  // logical k-block this lane fetches (swizzle inverse)

  const char* Ac = (const char*)A;
  const char* Wc = (const char*)WT;
  uint64_t gA[4], gB[4];
#pragma unroll
  for (int i = 0; i < 4; ++i) {
    int row = wid * 32 + i * 8 + rl;
    int arow = GATHER ? ptok[pairbase + row] : (pairbase + row);
    gA[i] = (uint64_t)arow * (KD * 2) + (uint64_t)kbl * 16;
    int brow = colbase + row;
    gB[i] = ((uint64_t)e * NOUT + brow) * (KD * 2) + (uint64_t)kbl * 16;
  }

  f32x4 acc[4][4];
  f32x4 zed = {0.f, 0.f, 0.f, 0.f};
#pragma unroll
  for (int a = 0; a < 4; ++a)
#pragma unroll
    for (int b = 0; b < 4; ++b) acc[a][b] = zed;

  for (int step = 0; step < KD / 64; ++step) {
    __syncthreads();
#pragma unroll
    for (int i = 0; i < 4; ++i)
      gload_lds16(Ac + gA[i] + (uint64_t)step * 128, (void*)&As[(wid * 32 + i * 8) * 64]);
#pragma unroll
    for (int i = 0; i < 4; ++i)
      gload_lds16(Wc + gB[i] + (uint64_t)step * 128, (void*)&Bs[(wid * 32 + i * 8) * 64]);
    __syncthreads();

#pragma unroll
    for (int s = 0; s < 2; ++s) {
      bf16x8 af[4], bfr[4];
#pragma unroll
      for (int tm = 0; tm < 4; ++tm) {
        int row = wm * 64 + tm * 16 + lm;
        int phys = (s * 4 + quad + l7) & 7;
        af[tm] = ldfrag(&As[row * 64 + phys * 8]);
      }
#pragma unroll
      for (int tn = 0; tn < 4; ++tn) {
        int col = wn * 64 + tn * 16 + lm;
        int phys = (s * 4 + quad + l7) & 7;
        bfr[tn] = ldfrag(&Bs[col * 64 + phys * 8]);
      }
#pragma unroll
      for (int tm = 0; tm < 4; ++tm)
#pragma unroll
        for (int tn = 0; tn < 4; ++tn)
          acc[tm][tn] = __builtin_amdgcn_mfma_f32_16x16x32_bf16(af[tm], bfr[tn], acc[tm][tn], 0, 0, 0);
    }
  }

  // epilogue: bias (+GELU), store bf16. C/D layout: col=lane&15, row=quad*4+i
#pragma unroll
  for (int tn = 0; tn < 4; ++tn) {
    int col = colbase + wn * 64 + tn * 16 + lm;
    float bv = bias[e * NOUT + col];
#pragma unroll
    for (int tm = 0; tm < 4; ++tm) {
      int row0 = pairbase + wm * 64 + tm * 16 + quad * 4;
#pragma unroll
      for (int i = 0; i < 4; ++i) {
        float vv = acc[tm][tn][i] + bv;
        if (DOGELU) vv = 0.5f * vv * (1.f + erff(vv * 0.70710678118654752f));
        Out[(size_t)(row0 + i) * NOUT + col] = bf16_rne(vv);
      }
    }
  }
}

// ---------------- combine: out[n] = w0*pairout[p0] + w1*pairout[p1] ----------
__global__ __launch_bounds__(256) void k_combine(const u16* __restrict__ pairout,
                                                 const float2* __restrict__ topw,
                                                 const int2* __restrict__ ppos,
                                                 float* __restrict__ out) {
  int n = blockIdx.x, t = threadIdx.x;
  int2 p = ppos[n];
  float2 w = topw[n];
  ushort4 a = ((const ushort4*)(pairout + (size_t)p.x * CDIM))[t];
  ushort4 b = ((const ushort4*)(pairout + (size_t)p.y * CDIM))[t];
  float4 o;
  o.x = w.x * bf2f(a.x) + w.y * bf2f(b.x);
  o.y = w.x * bf2f(a.y) + w.y * bf2f(b.y);
  o.z = w.x * bf2f(a.z) + w.y * bf2f(b.z);
  o.w = w.x * bf2f(a.w) + w.y * bf2f(b.w);
  ((float4*)(out + (size_t)n * CDIM))[t] = o;
}

// ---------------- launch ----------------
extern "C" void kernel_launch(void* const* d_in, const int* in_sizes, int n_in,
                              void* d_out, int out_size, void* d_ws, size_t ws_size,
                              hipStream_t stream) {
  const float* x  = (const float*)d_in[0];
  const float* wr = (const float*)d_in[1];
  const float* w1 = (const float*)d_in[2];
  const float* b1 = (const float*)d_in[3];
  const float* w2 = (const float*)d_in[4];
  const float* b2 = (const float*)d_in[5];
  float* out = (float*)d_out;
  char* ws = (char*)d_ws;

  // ws layout (total ~162 MiB; wt buffer shared by both transposes)
  int*    counts  = (int*)(ws + 0);
  int*    poff    = (int*)(ws + 64);
  int*    cursor  = (int*)(ws + 128);
  int*    ntiles  = (int*)(ws + 192);
  int*    tile_e  = (int*)(ws + 256);
  int*    tile_b  = (int*)(ws + 640);
  int2*   topi    = (int2*)(ws + 1024);          // 32 KB
  float2* topw    = (float2*)(ws + 33792);       // 32 KB
  int2*   ppos    = (int2*)(ws + 66560);         // 32 KB
  int*    ptok    = (int*)(ws + 99328);          // 36 KB
  u16*    xb      = (u16*)(ws + 136192);         // 8 MB
  u16*    h       = (u16*)(ws + 8524800);        // 75.5 MB
  u16*    wt      = (u16*)(ws + 84022272);       // 67.1 MB (shared)
  u16*    pairout = (u16*)(ws + 151131136);      // 18.9 MB  -> end 170,005,504

  hipMemsetAsync(ws, 0, 1024, stream);                 // counts/poff/cursor/tiles
  hipMemsetAsync(ws + 99328, 0, 36864, stream);        // ptok (pad rows -> token 0)

  k_router<<<NTOK, 64, 0, stream>>>(x, wr, topi, topw);
  k_count<<<NTOK / 256, 256, 0, stream>>>(topi, counts);
  k_scan<<<1, 64, 0, stream>>>(counts, poff, cursor, ntiles, tile_e, tile_b);
  k_scatter<<<NTOK / 256, 256, 0, stream>>>(topi, cursor, ptok, ppos);
  k_xcast<<<NTOK * CDIM / 4 / 256, 256, 0, stream>>>(x, xb);

  // w1: [E][C][D] -> wt [E][D][C]
  k_transpose<<<dim3(DDIM / 64, CDIM / 64, NEXP), 256, 0, stream>>>(w1, wt, CDIM, DDIM);
  k_gemm<CDIM, DDIM, true, true>
      <<<dim3(MAXTILE, DDIM / 128), 256, 0, stream>>>(xb, wt, b1, ntiles, tile_e, tile_b, ptok, h);

  // w2: [E][D][C] -> wt [E][C][D]
  k_transpose<<<dim3(CDIM / 64, DDIM / 64, NEXP), 256, 0, stream>>>(w2, wt, DDIM, CDIM);
  k_gemm<DDIM, CDIM, false, false>
      <<<dim3(MAXTILE, CDIM / 128), 256, 0, stream>>>(h, wt, b2, ntiles, tile_e, tile_b, ptok, pairout);

  k_combine<<<NTOK, 256, 0, stream>>>(pairout, topw, ppos, out);
}

// Round 3
// 577.378 us; speedup vs baseline: 2.2202x; 1.2038x over previous
//
#include <hip/hip_runtime.h>
#include <cstdint>

#define NTOK 4096
#define CDIM 1024
#define DDIM 4096
#define NEXP 8
#define PAIR_CAP 9216
#define MAXTILE 72

typedef __bf16 bf16x8 __attribute__((ext_vector_type(8)));
typedef float f32x4 __attribute__((ext_vector_type(4)));
typedef unsigned int u32x4 __attribute__((ext_vector_type(4)));
typedef unsigned short u16;

__device__ __forceinline__ u16 bf16_rne(float f) {
  unsigned u = __builtin_bit_cast(unsigned, f);
  u += 0x7fffu + ((u >> 16) & 1u);
  return (u16)(u >> 16);
}
__device__ __forceinline__ unsigned pk2(float a, float b) {
  return (unsigned)bf16_rne(a) | ((unsigned)bf16_rne(b) << 16);
}
__device__ __forceinline__ float bf2f(u16 v) {
  unsigned u = (unsigned)v << 16;
  return __builtin_bit_cast(float, u);
}
__device__ __forceinline__ bf16x8 ldfrag(const u16* p) {
  u32x4 v = *(const u32x4*)p;
  return __builtin_bit_cast(bf16x8, v);
}
__device__ __forceinline__ float gelu_f(float v) {
  // tanh-GELU: v * sigmoid(1.5957691216*(v + 0.044715 v^3)); max |err| ~3e-4
  float u = v + 0.044715f * v * v * v;
  return v / (1.f + __expf(-1.5957691216f * u));
}

typedef __attribute__((address_space(1))) const unsigned int as1_u32;
typedef __attribute__((address_space(3))) unsigned int as3_u32;
__device__ __forceinline__ void gload_lds16(const void* g, void* l) {
  __builtin_amdgcn_global_load_lds((as1_u32*)g, (as3_u32*)l, 16, 0, 0);
}

// ---------------- fused prep: router + xcast + transpose(s) ----------------
__device__ __forceinline__ void transpose_tile(const float* __restrict__ src0,
                                               u16* __restrict__ dst0, int K, int N,
                                               int kb, int nb, int t, float tile[64][65]) {
  const float* src = src0 + (size_t)kb * N + nb;
#pragma unroll
  for (int j = 0; j < 4; ++j) {
    int idx4 = t + j * 256;  // 1024 float4 = 64x64 floats
    int r = idx4 >> 4, c4 = idx4 & 15;
    float4 v = *(const float4*)&src[(size_t)r * N + c4 * 4];
    tile[r][c4 * 4 + 0] = v.x; tile[r][c4 * 4 + 1] = v.y;
    tile[r][c4 * 4 + 2] = v.z; tile[r][c4 * 4 + 3] = v.w;
  }
  __syncthreads();
  u16* dst = dst0 + (size_t)nb * K + kb;
#pragma unroll
  for (int j = 0; j < 8; ++j) {
    int idxp = t + j * 256;  // 2048 x ushort2
    int n = idxp >> 5, kp = idxp & 31;
    *(unsigned*)&dst[(size_t)n * K + kp * 2] = pk2(tile[kp * 2][n], tile[kp * 2 + 1][n]);
  }
}

#define RB 1024   // router blocks (4 tokens each)
#define XB 4096   // xcast blocks
#define TB 8192   // blocks per weight transpose

__global__ __launch_bounds__(256) void k_prep(
    const float* __restrict__ x, const float* __restrict__ wr,
    const float* __restrict__ w1, const float* __restrict__ w2,
    int2* __restrict__ topi, float2* __restrict__ topw,
    u16* __restrict__ xb, u16* __restrict__ wt1, u16* __restrict__ wt2) {
  __shared__ float tile[64][65];
  int b = blockIdx.x, t = threadIdx.x;
  if (b < RB) {
    // ---- router: 1 wave per token ----
    int wid = t >> 6, lane = t & 63;
    int n = b * 4 + wid;
    const float* xr = x + (size_t)n * CDIM;
    float acc[NEXP];
#pragma unroll
    for (int e = 0; e < NEXP; ++e) acc[e] = 0.f;
    for (int c = lane; c < CDIM; c += 64) {
      float xv = xr[c];
#pragma unroll
      for (int e = 0; e < NEXP; ++e) acc[e] += xv * wr[e * CDIM + c];
    }
#pragma unroll
    for (int e = 0; e < NEXP; ++e) {
      float v = acc[e];
#pragma unroll
      for (int off = 32; off > 0; off >>= 1) v += __shfl_xor(v, off, 64);
      acc[e] = v;
    }
    if (lane == 0) {
      int i1 = 0; float l1 = acc[0];
#pragma unroll
      for (int e = 1; e < NEXP; ++e) if (acc[e] > l1) { l1 = acc[e]; i1 = e; }
      int i2 = (i1 == 0) ? 1 : 0; float l2 = acc[i2];
#pragma unroll
      for (int e = 0; e < NEXP; ++e)
        if (e != i1 && acc[e] > l2) { l2 = acc[e]; i2 = e; }
      float wa = 1.f / (1.f + __expf(l2 - l1));
      topi[n] = make_int2(i1, i2);
      topw[n] = make_float2(wa, 1.f - wa);
    }
  } else if (b < RB + XB) {
    // ---- x fp32 -> bf16 ----
    int i = (b - RB) * 256 + t;
    float4 v = ((const float4*)x)[i];
    ushort4 o;
    o.x = bf16_rne(v.x); o.y = bf16_rne(v.y); o.z = bf16_rne(v.z); o.w = bf16_rne(v.w);
    ((ushort4*)xb)[i] = o;
  } else if (b < RB + XB + TB) {
    // ---- w1 [E][1024][4096] -> wt1 [E][4096][1024] ----
    int idx = b - (RB + XB);
    int e = idx >> 10, rem = idx & 1023;
    int nb = (rem & 63) * 64, kb = (rem >> 6) * 64;
    transpose_tile(w1 + (size_t)e * CDIM * DDIM, wt1 + (size_t)e * DDIM * CDIM,
                   CDIM, DDIM, kb, nb, t, tile);
  } else {
    // ---- w2 [E][4096][1024] -> wt2 [E][1024][4096] (big-ws path only) ----
    int idx = b - (RB + XB + TB);
    int e = idx >> 10, rem = idx & 1023;
    int nb = (rem & 15) * 64, kb = (rem >> 4) * 64;
    transpose_tile(w2 + (size_t)e * DDIM * CDIM, wt2 + (size_t)e * CDIM * DDIM,
                   DDIM, CDIM, kb, nb, t, tile);
  }
}

// standalone transpose for the small-ws fallback (w2 -> shared wt after gemm1)
__global__ __launch_bounds__(256) void k_transpose_w2(const float* __restrict__ in,
                                                      u16* __restrict__ out) {
  __shared__ float tile[64][65];
  int e = blockIdx.z;
  transpose_tile(in + (size_t)e * DDIM * CDIM, out + (size_t)e * CDIM * DDIM,
                 DDIM, CDIM, blockIdx.y * 64, blockIdx.x * 64, threadIdx.x, tile);
}

// ---------------- bucketing (single block) ----------------
__global__ void k_bucket(const int2* __restrict__ topi, int* __restrict__ ptok,
                         int2* __restrict__ ppos, int* __restrict__ ntiles,
                         int* __restrict__ tile_e, int* __restrict__ tile_b) {
  __shared__ int cnt[NEXP], cur[NEXP];
  int t = threadIdx.x;
  if (t < NEXP) cnt[t] = 0;
  __syncthreads();
  for (int n = t; n < NTOK; n += 1024) {
    int2 tv = topi[n];
    atomicAdd(&cnt[tv.x], 1);
    atomicAdd(&cnt[tv.y], 1);
  }
  __syncthreads();
  if (t == 0) {
    int o = 0, nt = 0;
    for (int e = 0; e < NEXP; ++e) {
      cur[e] = o;
      int cap = (cnt[e] + 127) & ~127;
      for (int tb = 0; tb < cap; tb += 128) { tile_e[nt] = e; tile_b[nt] = o + tb; ++nt; }
      o += cap;
    }
    *ntiles = nt;
  }
  __syncthreads();
  for (int n = t; n < NTOK; n += 1024) {
    int2 tv = topi[n];
    int p0 = atomicAdd(&cur[tv.x], 1); ptok[p0] = n;
    int p1 = atomicAdd(&cur[tv.y], 1); ptok[p1] = n;
    ppos[n] = make_int2(p0, p1);
  }
}

// ---------------- unified MFMA GEMM (m97 structure) ----------------
// KROW: A row stride (elems). KLEN: k extent per block (split-K via blockIdx.z).
// COLX: col tile in blockIdx.x (col-fastest dispatch for A-tile L2 reuse).
template <int KROW, int KLEN, int NOUT, bool GATHER, bool GELUBIAS, bool COLX>
__global__ __launch_bounds__(256) void k_gemm(
    const u16* __restrict__ A, const u16* __restrict__ WT,
    const float* __restrict__ bias, const int* __restrict__ ntiles,
    const int* __restrict__ tile_e, const int* __restrict__ tile_base,
    const int* __restrict__ ptok, u16* __restrict__ Out) {
  int tileIdx = COLX ? blockIdx.y : blockIdx.x;
  int colIdx = COLX ? blockIdx.x : blockIdx.y;
  if (tileIdx >= *ntiles) return;
  int e = tile_e[tileIdx];
  int pairbase = tile_base[tileIdx];
  int colbase = colIdx * 128;
  int kbase = blockIdx.z * KLEN;
  u16* OutZ = Out + (size_t)blockIdx.z * ((size_t)PAIR_CAP * NOUT);

  __shared__ __align__(16) u16 As[128 * 64];
  __shared__ __align__(16) u16 Bs[128 * 64];

  int t = threadIdx.x;
  int wid = t >> 6, lane = t & 63;
  int quad = lane >> 4, lm = lane & 15, l7 = lane & 7;
  int wm = wid & 1, wn = wid >> 1;
  int rl = lane >> 3, q = lane & 7;
  int kbl = (q - rl) & 7;  // logical k-block for swizzled LDS slot q

  const char* Ac = (const char*)A;
  const char* Wc = (const char*)WT;
  uint64_t gA[4], gB[4];
#pragma unroll
  for (int i = 0; i < 4; ++i) {
    int row = wid * 32 + i * 8 + rl;
    int arow = GATHER ? ptok[pairbase + row] : (pairbase + row);
    gA[i] = (uint64_t)arow * (KROW * 2) + (uint64_t)kbase * 2 + (uint64_t)kbl * 16;
    int brow = colbase + row;
    gB[i] = ((uint64_t)e * NOUT + brow) * (KROW * 2) + (uint64_t)kbase * 2 + (uint64_t)kbl * 16;
  }

  f32x4 acc[4][4];
  f32x4 zed = {0.f, 0.f, 0.f, 0.f};
#pragma unroll
  for (int a = 0; a < 4; ++a)
#pragma unroll
    for (int b = 0; b < 4; ++b) acc[a][b] = zed;

  for (int step = 0; step < KLEN / 64; ++step) {
    __syncthreads();
#pragma unroll
    for (int i = 0; i < 4; ++i)
      gload_lds16(Ac + gA[i] + (uint64_t)step * 128, (void*)&As[(wid * 32 + i * 8) * 64]);
#pragma unroll
    for (int i = 0; i < 4; ++i)
      gload_lds16(Wc + gB[i] + (uint64_t)step * 128, (void*)&Bs[(wid * 32 + i * 8) * 64]);
    __syncthreads();

#pragma unroll
    for (int s = 0; s < 2; ++s) {
      bf16x8 af[4], bfr[4];
#pragma unroll
      for (int tm = 0; tm < 4; ++tm) {
        int row = wm * 64 + tm * 16 + lm;
        int phys = (s * 4 + quad + l7) & 7;
        af[tm] = ldfrag(&As[row * 64 + phys * 8]);
      }
#pragma unroll
      for (int tn = 0; tn < 4; ++tn) {
        int col = wn * 64 + tn * 16 + lm;
        int phys = (s * 4 + quad + l7) & 7;
        bfr[tn] = ldfrag(&Bs[col * 64 + phys * 8]);
      }
#pragma unroll
      for (int tm = 0; tm < 4; ++tm)
#pragma unroll
        for (int tn = 0; tn < 4; ++tn)
          acc[tm][tn] = __builtin_amdgcn_mfma_f32_16x16x32_bf16(af[tm], bfr[tn], acc[tm][tn], 0, 0, 0);
    }
  }

  // epilogue. C/D layout: col=lane&15, row=quad*4+i
#pragma unroll
  for (int tn = 0; tn < 4; ++tn) {
    int col = colbase + wn * 64 + tn * 16 + lm;
    float bv = 0.f;
    if constexpr (GELUBIAS) bv = bias[e * NOUT + col];
#pragma unroll
    for (int tm = 0; tm < 4; ++tm) {
      int row0 = pairbase + wm * 64 + tm * 16 + quad * 4;
#pragma unroll
      for (int i = 0; i < 4; ++i) {
        float vv = acc[tm][tn][i];
        if constexpr (GELUBIAS) vv = gelu_f(vv + bv);
        OutZ[(size_t)(row0 + i) * NOUT + col] = bf16_rne(vv);
      }
    }
  }
}

// ---------------- combine: out[n] = sum_k w_k * (sum_parts P[p_k] + b2[e_k]) --
__global__ __launch_bounds__(256) void k_combine(
    const u16* __restrict__ P, const float2* __restrict__ topw,
    const int2* __restrict__ ppos, const int2* __restrict__ topi,
    const float* __restrict__ b2, float* __restrict__ out, int nparts) {
  int n = blockIdx.x, t = threadIdx.x;
  int2 p = ppos[n];
  float2 w = topw[n];
  int2 ei = topi[n];
  ushort4 a0 = ((const ushort4*)(P + (size_t)p.x * CDIM))[t];
  ushort4 b0 = ((const ushort4*)(P + (size_t)p.y * CDIM))[t];
  float ax = bf2f(a0.x), ay = bf2f(a0.y), az = bf2f(a0.z), aw = bf2f(a0.w);
  float bx = bf2f(b0.x), by = bf2f(b0.y), bz = bf2f(b0.z), bw = bf2f(b0.w);
  if (nparts == 2) {
    const u16* P1 = P + (size_t)PAIR_CAP * CDIM;
    ushort4 a1 = ((const ushort4*)(P1 + (size_t)p.x * CDIM))[t];
    ushort4 b1v = ((const ushort4*)(P1 + (size_t)p.y * CDIM))[t];
    ax += bf2f(a1.x); ay += bf2f(a1.y); az += bf2f(a1.z); aw += bf2f(a1.w);
    bx += bf2f(b1v.x); by += bf2f(b1v.y); bz += bf2f(b1v.z); bw += bf2f(b1v.w);
  }
  float4 c0 = ((const float4*)(b2 + (size_t)ei.x * CDIM))[t];
  float4 c1 = ((const float4*)(b2 + (size_t)ei.y * CDIM))[t];
  float4 o;
  o.x = w.x * (ax + c0.x) + w.y * (bx + c1.x);
  o.y = w.x * (ay + c0.y) + w.y * (by + c1.y);
  o.z = w.x * (az + c0.z) + w.y * (bz + c1.z);
  o.w = w.x * (aw + c0.w) + w.y * (bw + c1.w);
  ((float4*)(out + (size_t)n * CDIM))[t] = o;
}

// ---------------- launch ----------------
extern "C" void kernel_launch(void* const* d_in, const int* in_sizes, int n_in,
                              void* d_out, int out_size, void* d_ws, size_t ws_size,
                              hipStream_t stream) {
  const float* x  = (const float*)d_in[0];
  const float* wr = (const float*)d_in[1];
  const float* w1 = (const float*)d_in[2];
  const float* b1 = (const float*)d_in[3];
  const float* w2 = (const float*)d_in[4];
  const float* b2 = (const float*)d_in[5];
  float* out = (float*)d_out;
  char* ws = (char*)d_ws;

  // ws layout:
  //   [0,1024)       ntiles/tile_e/tile_b
  //   topi 32K, topw 32K, ppos 32K, ptok 36K        -> end 136192
  //   xb   8,388,608                                 -> end 8,524,800
  //   h    75,497,472                                -> end 84,022,272
  //   wt1  67,108,864                                -> end 151,131,136
  // big  (ws >= 218,240,000): wt2 67,108,864         -> end 218,240,000
  //       split-K partials (37,748,736) overlay wt1 (dead after gemm1)
  // small (proven 170,005,504): wt1 shared for w2; pairout 18,874,368 at
  //       151,131,136 -> end 170,005,504
  int*    ntiles = (int*)(ws + 192);
  int*    tile_e = (int*)(ws + 256);
  int*    tile_b = (int*)(ws + 640);
  int2*   topi   = (int2*)(ws + 1024);
  float2* topw   = (float2*)(ws + 33792);
  int2*   ppos   = (int2*)(ws + 66560);
  int*    ptok   = (int*)(ws + 99328);
  u16*    xb     = (u16*)(ws + 136192);
  u16*    h      = (u16*)(ws + 8524800);
  u16*    wt1    = (u16*)(ws + 84022272);
  u16*    wt2    = (u16*)(ws + 151131136);
  u16*    parts  = (u16*)(ws + 84022272);   // overlays wt1 (big path)
  u16*    pairout= (u16*)(ws + 151131136);  // small path

  bool big = ws_size >= 218240000ULL;

  hipMemsetAsync(ws + 99328, 0, 36864, stream);  // ptok: pad rows -> token 0

  k_prep<<<big ? (RB + XB + 2 * TB) : (RB + XB + TB), 256, 0, stream>>>(
      x, wr, w1, w2, topi, topw, xb, wt1, wt2);
  k_bucket<<<1, 1024, 0, stream>>>(topi, ptok, ppos, ntiles, tile_e, tile_b);

  k_gemm<CDIM, CDIM, DDIM, true, true, false>
      <<<dim3(MAXTILE, DDIM / 128, 1), 256, 0, stream>>>(
          xb, wt1, b1, ntiles, tile_e, tile_b, ptok, h);

  if (big) {
    k_gemm<DDIM, DDIM / 2, CDIM, false, false, true>
        <<<dim3(CDIM / 128, MAXTILE, 2), 256, 0, stream>>>(
            h, wt2, nullptr, ntiles, tile_e, tile_b, ptok, parts);
    k_combine<<<NTOK, 256, 0, stream>>>(parts, topw, ppos, topi, b2, out, 2);
  } else {
    k_transpose_w2<<<dim3(CDIM / 64, DDIM / 64, NEXP), 256, 0, stream>>>(w2, wt1);
    k_gemm<DDIM, DDIM, CDIM, false, false, true>
        <<<dim3(CDIM / 128, MAXTILE, 1), 256, 0, stream>>>(
            h, wt1, nullptr, ntiles, tile_e, tile_b, ptok, pairout);
    k_combine<<<NTOK, 256, 0, stream>>>(pairout, topw, ppos, topi, b2, out, 1);
  }
}